// Round 19
// baseline (149.934 us; speedup 1.0000x reference)
//
#include <hip/hip_runtime.h>
#include <hip/hip_bf16.h>

typedef __attribute__((ext_vector_type(4))) float f32x4;
typedef __attribute__((ext_vector_type(8))) short bf16x8;

#define H 1024        // hidden / K
#define NTOT 1280     // nq*64 + nkv*64*2
#define BM 128
#define BN 128
#define BK 32
#define NST 32        // H / BK k-steps
#define NTILES 10     // NTOT / BN

static __device__ __forceinline__ unsigned short f2bf(float f) {
    __hip_bfloat16 b = __float2bfloat16(f);
    return __builtin_bit_cast(unsigned short, b);
}

#define GLOAD_LDS16(g, l)                                                     \
    __builtin_amdgcn_global_load_lds(                                         \
        (const __attribute__((address_space(1))) void*)(g),                   \
        (__attribute__((address_space(3))) void*)(l), 16, 0, 0)

// ---------------------------------------------------------------------------
// Kernel 1 (merged prologue, R17): blocks [0,nrms) RMSNorm x->h; blocks
// [nrms, nrms+320) build Bt[n][k] = bf16((1+lnw[k]) * W[k][n]).
// ---------------------------------------------------------------------------
__global__ __launch_bounds__(256) void k_pre(const float* __restrict__ x,
                                             const float* __restrict__ wq,
                                             const float* __restrict__ wk,
                                             const float* __restrict__ wv,
                                             const float* __restrict__ lnw,
                                             __hip_bfloat16* __restrict__ h,
                                             __hip_bfloat16* __restrict__ Bt,
                                             int nrms) {
    __shared__ float l[64][65];
    const int t = threadIdx.x;

    if ((int)blockIdx.x < nrms) {
        const int wave = t >> 6;
        const int lane = t & 63;
        const size_t row = (size_t)blockIdx.x * 4 + wave;

        const float4* xr = (const float4*)(x + row * H);
        float4 v[4];
        float ss = 0.f;
#pragma unroll
        for (int i = 0; i < 4; ++i) {
            v[i] = xr[lane + 64 * i];
            ss += v[i].x * v[i].x + v[i].y * v[i].y + v[i].z * v[i].z + v[i].w * v[i].w;
        }
#pragma unroll
        for (int o = 1; o < 64; o <<= 1) ss += __shfl_xor(ss, o);
        const float sc = rsqrtf(ss * (1.0f / H) + 1e-6f);

        ushort4* hr = (ushort4*)(h + row * H);
#pragma unroll
        for (int i = 0; i < 4; ++i) {
            ushort4 o4;
            o4.x = f2bf(v[i].x * sc);
            o4.y = f2bf(v[i].y * sc);
            o4.z = f2bf(v[i].z * sc);
            o4.w = f2bf(v[i].w * sc);
            hr[lane + 64 * i] = o4;
        }
    } else {
        const int b = (int)blockIdx.x - nrms;     // 0..319
        const int kt = b & 15;
        const int ntl = b >> 4;
        const int k0 = kt * 64, n0 = ntl * 64;
        const float* src; int ldn, nb;
        if (n0 < 1024)      { src = wq; ldn = 1024; nb = n0; }
        else if (n0 < 1152) { src = wk; ldn = 128;  nb = n0 - 1024; }
        else                { src = wv; ldn = 128;  nb = n0 - 1152; }
        const int nl = t & 63, kl = t >> 6;
#pragma unroll
        for (int i = 0; i < 16; ++i) {
            const int k = kl + i * 4;
            l[k][nl] = (1.0f + lnw[k0 + k]) * src[(size_t)(k0 + k) * ldn + nb + nl];
        }
        __syncthreads();
        const int k2 = t & 63, n2 = t >> 6;
#pragma unroll
        for (int i = 0; i < 16; ++i) {
            const int n = n2 + i * 4;
            Bt[(size_t)(n0 + n) * 1024 + k0 + k2] = __float2bfloat16(l[k2][n]);
        }
    }
}

// ---------------------------------------------------------------------------
// Kernel 2: GEMM out[M][1280] = h[M][1024] @ Bt^T.  (R19: ring-3, 1 barrier
// per BK=32 step.) Ring-2 forced a mid-tile barrier + lgkm drain BETWEEN
// reads and MFMAs (the staged buffer was the one just read). Ring-3 stages
// into a buffer untouched this step: per step only the seam barrier, and the
// rule-#18 own-reads drain moves AFTER the MFMAs where it is free.
//   STEP(kt): vmcnt(4); BAR; read 8 frags; STAGE((kt+2)%3, kt+2);
//             prio1; 16 MFMA; prio0; lgkm(0)+fence.
// Race audit: buf (kt+2)%3 last read at step kt-1; every wave drained its
// reads (end-of-step lgkm0) before BAR(kt) -> write-after-read safe. vmcnt
// ledger: 4 gloads/step, 2 steps outstanding -> seam vmcnt(4), drain only
// at the last step. LDS 3 x 16KB = 48KB -> 2 blocks/CU. R13's verified
// conflict-free row-pair swizzle for the 128x32 tiles (both sides).
// 4 waves 2x2 (64x64/wave, acc[4][4]=64 AGPR). XCD chunking, grid 2560.
// ---------------------------------------------------------------------------
__global__ __launch_bounds__(256, 2) void k_gemm(const __hip_bfloat16* __restrict__ A,
                                                 const __hip_bfloat16* __restrict__ Bt,
                                                 float* __restrict__ out, int rows) {
    __shared__ __align__(16) char smem[49152];  // 3 bufs x (A 8KB | B 8KB)

    const int tid = threadIdx.x;
    const int lane = tid & 63;
    const int wid = tid >> 6;
    const int wm = wid >> 1;   // 0..1 (64 rows each)
    const int wn = wid & 1;    // 0..1 (64 cols each)

    // bijective XCD chunk swizzle (2560 % 8 == 0), nt fastest
    const int cpx = gridDim.x >> 3;                 // 320
    const int wg = (blockIdx.x & 7) * cpx + (blockIdx.x >> 3);
    const int nt = wg % NTILES;
    const int mt = wg / NTILES;
    const size_t m0 = (size_t)mt * BM;

    // ---- staging source pointers (R13 row-pair swizzle): dest slot d ->
    //      rp=d>>3; s=(d&7)^(rp&7); row=rp*2+(s>>2); kg=s&3 (16B col group)
    const char* aSrc[2];
    const char* bSrc[2];
#pragma unroll
    for (int j = 0; j < 2; ++j) {
        const int d = tid + j * 256;
        const int rp = d >> 3, s = (d & 7) ^ (rp & 7);
        const int row = rp * 2 + (s >> 2), kg = s & 3;
        aSrc[j] = (const char*)A + (m0 + row) * (size_t)(H * 2) + kg * 16;
        bSrc[j] = (const char*)Bt + ((size_t)nt * BN + row) * (size_t)(H * 2) + kg * 16;
    }

#define STAGE(buf, kt)                                                        \
    {                                                                         \
        _Pragma("unroll") for (int j = 0; j < 2; ++j)                         \
            GLOAD_LDS16(aSrc[j] + (size_t)(kt) * 64,                          \
                        smem + (buf) * 16384 + (tid + j * 256) * 16);         \
        _Pragma("unroll") for (int j = 0; j < 2; ++j)                         \
            GLOAD_LDS16(bSrc[j] + (size_t)(kt) * 64,                          \
                        smem + (buf) * 16384 + 8192 + (tid + j * 256) * 16);  \
    }

    // ---- fragment read base (R13 formula, verified conflict-free):
    //      16-row group j lives at bytes j*1024..+1023
    const int fb = ((lane & 15) >> 1) * 128
                 + (((((lane & 1) << 2) + (lane >> 4)) ^ ((lane & 15) >> 1)) << 4);

    f32x4 acc[4][4] = {};

#define STEP(buf, sbuf, kt, DS, VM)                                           \
    {                                                                         \
        const char* aL = smem + (buf) * 16384;                                \
        const char* bL = aL + 8192;                                           \
        asm volatile("s_waitcnt vmcnt(" VM ")" ::: "memory");                 \
        __builtin_amdgcn_s_barrier();                                         \
        __builtin_amdgcn_sched_barrier(0);                                    \
        bf16x8 af[4], bfv[4];                                                 \
        _Pragma("unroll") for (int mi = 0; mi < 4; ++mi)                      \
            af[mi] = *(const bf16x8*)(aL + fb + (wm * 4 + mi) * 1024);        \
        _Pragma("unroll") for (int ni = 0; ni < 4; ++ni)                      \
            bfv[ni] = *(const bf16x8*)(bL + fb + (wn * 4 + ni) * 1024);       \
        if (DS) STAGE(sbuf, (kt) + 2);                                        \
        __builtin_amdgcn_s_setprio(1);                                        \
        _Pragma("unroll") for (int mi = 0; mi < 4; ++mi)                      \
            _Pragma("unroll") for (int ni = 0; ni < 4; ++ni)                  \
                acc[mi][ni] = __builtin_amdgcn_mfma_f32_16x16x32_bf16(        \
                    af[mi], bfv[ni], acc[mi][ni], 0, 0, 0);                   \
        __builtin_amdgcn_s_setprio(0);                                        \
        asm volatile("s_waitcnt lgkmcnt(0)" ::: "memory");                    \
        __builtin_amdgcn_sched_barrier(0);    /* rule #18: own reads drained */\
    }

    // ---- prologue: stage steps 0 and 1 ----
    STAGE(0, 0);
    STAGE(1, 1);

    // ---- main loop: 32 steps, ring-3, one barrier per step ----
    for (int kt = 0; kt < 30; kt += 3) {
        STEP(0, 2, kt, 1, "4");
        STEP(1, 0, kt + 1, 1, "4");
        STEP(2, 1, kt + 2, 1, "4");
    }
    STEP(0, 2, 30, 0, "4");
    STEP(1, 0, 31, 0, "0");

    // ---- epilogue: split q/k/v regions (wn*64 never straddles boundaries) ----
    const size_t QSZ = (size_t)rows * 1024;
    const size_t KSZ = (size_t)rows * 128;
    const int colg0 = nt * BN + wn * 64;
    float* op;
    int ldc, cb0;
    if (colg0 < 1024)      { op = out;             ldc = 1024; cb0 = colg0; }
    else if (colg0 < 1152) { op = out + QSZ;       ldc = 128;  cb0 = colg0 - 1024; }
    else                   { op = out + QSZ + KSZ; ldc = 128;  cb0 = colg0 - 1152; }

    const size_t r0 = m0 + wm * 64 + ((lane >> 4) * 4);
    const int cc0 = cb0 + (lane & 15);
#pragma unroll
    for (int mi = 0; mi < 4; ++mi)
#pragma unroll
        for (int ni = 0; ni < 4; ++ni)
#pragma unroll
            for (int rr = 0; rr < 4; ++rr)
                op[(r0 + mi * 16 + rr) * (size_t)ldc + cc0 + ni * 16] = acc[mi][ni][rr];
}

// ---------------------------------------------------------------------------
extern "C" void kernel_launch(void* const* d_in, const int* in_sizes, int n_in,
                              void* d_out, int out_size, void* d_ws, size_t ws_size,
                              hipStream_t stream) {
    const float* x   = (const float*)d_in[0];
    const float* lnw = (const float*)d_in[1];
    const float* wq  = (const float*)d_in[2];
    const float* wk  = (const float*)d_in[3];
    const float* wv  = (const float*)d_in[4];
    float* out = (float*)d_out;

    const int rows = in_sizes[0] / H;  // B*S = 32768

    __hip_bfloat16* Bt = (__hip_bfloat16*)d_ws;                               // 2.62 MB
    __hip_bfloat16* h  = (__hip_bfloat16*)((char*)d_ws + (size_t)NTOT * H * 2);

    const int nrms = rows / 4;  // 8192
    k_pre<<<nrms + 320, 256, 0, stream>>>(x, wq, wk, wv, lnw, h, Bt, nrms);
    k_gemm<<<(rows / BM) * NTILES, 256, 0, stream>>>(h, Bt, out, rows);
}

// Round 20
// 135.754 us; speedup vs baseline: 1.1045x; 1.1045x over previous
//
#include <hip/hip_runtime.h>
#include <hip/hip_bf16.h>

typedef __attribute__((ext_vector_type(4))) float f32x4;
typedef __attribute__((ext_vector_type(8))) short bf16x8;

#define H 1024        // hidden / K
#define NTOT 1280     // nq*64 + nkv*64*2
#define BM 128
#define BN 128
#define BK 64
#define NKT 16        // H / BK
#define NTILES 10     // NTOT / BN

static __device__ __forceinline__ unsigned short f2bf(float f) {
    __hip_bfloat16 b = __float2bfloat16(f);
    return __builtin_bit_cast(unsigned short, b);
}

#define GLOAD_LDS16(g, l)                                                     \
    __builtin_amdgcn_global_load_lds(                                         \
        (const __attribute__((address_space(1))) void*)(g),                   \
        (__attribute__((address_space(3))) void*)(l), 16, 0, 0)

// ---------------------------------------------------------------------------
// Kernel 1 (merged prologue): blocks [0, nrms) do RMSNorm (one wave per
// row, 4 rows/block); blocks [nrms, nrms+320) build the transposed fused
// weight Bt[n][k] = bf16((1+lnw[k]) * W[k][n]). Merging removes one launch
// boundary and overlaps wprep with rms. Both at HBM BW roofline (~28 us).
// ---------------------------------------------------------------------------
__global__ __launch_bounds__(256) void k_pre(const float* __restrict__ x,
                                             const float* __restrict__ wq,
                                             const float* __restrict__ wk,
                                             const float* __restrict__ wv,
                                             const float* __restrict__ lnw,
                                             __hip_bfloat16* __restrict__ h,
                                             __hip_bfloat16* __restrict__ Bt,
                                             int nrms) {
    __shared__ float l[64][65];
    const int t = threadIdx.x;

    if ((int)blockIdx.x < nrms) {
        // ---- RMSNorm: x (fp32) -> h (bf16), (1+lnw) folded into weights ----
        const int wave = t >> 6;
        const int lane = t & 63;
        const size_t row = (size_t)blockIdx.x * 4 + wave;

        const float4* xr = (const float4*)(x + row * H);
        float4 v[4];
        float ss = 0.f;
#pragma unroll
        for (int i = 0; i < 4; ++i) {
            v[i] = xr[lane + 64 * i];
            ss += v[i].x * v[i].x + v[i].y * v[i].y + v[i].z * v[i].z + v[i].w * v[i].w;
        }
#pragma unroll
        for (int o = 1; o < 64; o <<= 1) ss += __shfl_xor(ss, o);
        const float sc = rsqrtf(ss * (1.0f / H) + 1e-6f);

        ushort4* hr = (ushort4*)(h + row * H);
#pragma unroll
        for (int i = 0; i < 4; ++i) {
            ushort4 o4;
            o4.x = f2bf(v[i].x * sc);
            o4.y = f2bf(v[i].y * sc);
            o4.z = f2bf(v[i].z * sc);
            o4.w = f2bf(v[i].w * sc);
            hr[lane + 64 * i] = o4;
        }
    } else {
        // ---- weight prep via LDS transpose tile ----
        const int b = (int)blockIdx.x - nrms;     // 0..319
        const int kt = b & 15;                    // 16 k-tiles
        const int ntl = b >> 4;                   // 20 n-tiles
        const int k0 = kt * 64, n0 = ntl * 64;
        const float* src; int ldn, nb;
        if (n0 < 1024)      { src = wq; ldn = 1024; nb = n0; }
        else if (n0 < 1152) { src = wk; ldn = 128;  nb = n0 - 1024; }
        else                { src = wv; ldn = 128;  nb = n0 - 1152; }
        const int nl = t & 63, kl = t >> 6;
#pragma unroll
        for (int i = 0; i < 16; ++i) {
            const int k = kl + i * 4;
            l[k][nl] = (1.0f + lnw[k0 + k]) * src[(size_t)(k0 + k) * ldn + nb + nl];
        }
        __syncthreads();
        const int k2 = t & 63, n2 = t >> 6;
#pragma unroll
        for (int i = 0; i < 16; ++i) {
            const int n = n2 + i * 4;
            Bt[(size_t)(n0 + n) * 1024 + k0 + k2] = __float2bfloat16(l[k2][n]);
        }
    }
}

// ---------------------------------------------------------------------------
// Kernel 2: GEMM out[M][1280] = h[M][1024] @ Bt^T.  (R16 — session best.)
// 256-thr blocks (4 waves 2x2), BM=BN=128, 64KB LDS ring-2, acc[4][4]=64
// AGPR -> 2 independent blocks/CU (epilogue of one overlaps the K-loop of
// the other). 2 barriers/tile, counted vmcnt(8), T2 both-sides swizzle,
// XCD chunking nt-fastest, grid 2560 = 5 exact rounds. Rule-#18
// sched_barrier(0) fence before the mid-tile barrier.
// Structural note: GEMM sits at the barrier-synced serial-sum ceiling
// (MFMA 1242 + LDS ~1800 cyc/K-tile, MfmaUtil ~33%); 10+ schedule variants
// (rings, phases, B-paths, occupancy, wave/MFMA shapes) all land 107-122 us.
// ---------------------------------------------------------------------------
__global__ __launch_bounds__(256, 2) void k_gemm(const __hip_bfloat16* __restrict__ A,
                                                 const __hip_bfloat16* __restrict__ Bt,
                                                 float* __restrict__ out, int rows) {
    __shared__ __align__(16) char smem[65536];  // 2 bufs x (A 16KB | B 16KB)

    const int tid = threadIdx.x;
    const int lane = tid & 63;
    const int wid = tid >> 6;
    const int wm = wid >> 1;   // 0..1 (64 rows each)
    const int wn = wid & 1;    // 0..1 (64 cols each)

    // bijective XCD chunk swizzle (2560 % 8 == 0), nt fastest
    const int cpx = gridDim.x >> 3;                 // 320
    const int wg = (blockIdx.x & 7) * cpx + (blockIdx.x >> 3);
    const int nt = wg % NTILES;
    const int mt = wg / NTILES;
    const size_t m0 = (size_t)mt * BM;

    // staging: thread t covers row (t>>3)+q*32 (q=0..3), 16B at (t&7)*16,
    // source col pre-swizzled by ((row&7)<<4)  (both-sides involution)
    const int r = tid >> 3;                         // 0..31
    const int cswz = ((tid & 7) * 16) ^ ((r & 7) << 4);
    const char* aG = (const char*)A + (m0 + r) * (size_t)(H * 2) + cswz;
    const char* bG = (const char*)Bt + ((size_t)nt * BN + r) * (size_t)(H * 2) + cswz;

#define STAGE(buf, kt)                                                        \
    {                                                                         \
        _Pragma("unroll") for (int q = 0; q < 4; ++q)                         \
            GLOAD_LDS16(aG + (size_t)(kt) * 128 + (size_t)q * 32 * (H * 2),   \
                        smem + (buf) * 32768 + q * 4096 + tid * 16);          \
        _Pragma("unroll") for (int q = 0; q < 4; ++q)                         \
            GLOAD_LDS16(bG + (size_t)(kt) * 128 + (size_t)q * 32 * (H * 2),   \
                        smem + (buf) * 32768 + 16384 + q * 4096 + tid * 16);  \
    }

    // fragment read addressing (swizzled)
    const int rowA = wm * 64 + (lane & 15);
    const int rowB = wn * 64 + (lane & 15);
    const int xm = (lane & 7) << 4;
    const int c0 = (((lane >> 4) * 16)) ^ xm;
    const int c1 = (64 + ((lane >> 4) * 16)) ^ xm;

    f32x4 acc[4][4] = {};

#define TILE(cur, kt, DS, VM)                                                 \
    {                                                                         \
        const char* aL = smem + (cur) * 32768;                                \
        const char* bL = aL + 16384;                                          \
        asm volatile("s_waitcnt vmcnt(" VM ")" ::: "memory");                 \
        __builtin_amdgcn_s_barrier();                                         \
        __builtin_amdgcn_sched_barrier(0);                                    \
        bf16x8 a0[4], b0[4];                                                  \
        _Pragma("unroll") for (int mi = 0; mi < 4; ++mi)                      \
            a0[mi] = *(const bf16x8*)(aL + (rowA + mi * 16) * 128 + c0);      \
        _Pragma("unroll") for (int ni = 0; ni < 4; ++ni)                      \
            b0[ni] = *(const bf16x8*)(bL + (rowB + ni * 16) * 128 + c0);      \
        bf16x8 a1[4], b1[4];                                                  \
        _Pragma("unroll") for (int mi = 0; mi < 4; ++mi)                      \
            a1[mi] = *(const bf16x8*)(aL + (rowA + mi * 16) * 128 + c1);      \
        _Pragma("unroll") for (int ni = 0; ni < 4; ++ni)                      \
            b1[ni] = *(const bf16x8*)(bL + (rowB + ni * 16) * 128 + c1);      \
        __builtin_amdgcn_s_setprio(1);                                        \
        _Pragma("unroll") for (int mi = 0; mi < 4; ++mi)                      \
            _Pragma("unroll") for (int ni = 0; ni < 4; ++ni)                  \
                acc[mi][ni] = __builtin_amdgcn_mfma_f32_16x16x32_bf16(        \
                    a0[mi], b0[ni], acc[mi][ni], 0, 0, 0);                    \
        __builtin_amdgcn_s_setprio(0);                                        \
        asm volatile("s_waitcnt lgkmcnt(0)" ::: "memory");                    \
        __builtin_amdgcn_sched_barrier(0);    /* rule #18 fence */            \
        __builtin_amdgcn_s_barrier();                                         \
        __builtin_amdgcn_sched_barrier(0);                                    \
        if (DS) STAGE(cur, (kt) + 2);                                         \
        __builtin_amdgcn_s_setprio(1);                                        \
        _Pragma("unroll") for (int mi = 0; mi < 4; ++mi)                      \
            _Pragma("unroll") for (int ni = 0; ni < 4; ++ni)                  \
                acc[mi][ni] = __builtin_amdgcn_mfma_f32_16x16x32_bf16(        \
                    a1[mi], b1[ni], acc[mi][ni], 0, 0, 0);                    \
        __builtin_amdgcn_s_setprio(0);                                        \
    }

    // prologue: stage tiles 0 and 1
    STAGE(0, 0);
    STAGE(1, 1);

    // main loop: ring-2, 2 barriers/tile, loads never drained mid-loop
    for (int kt = 0; kt < NKT - 4; kt += 2) {
        TILE(0, kt, 1, "8");
        TILE(1, kt + 1, 1, "8");
    }
    TILE(0, NKT - 4, 1, "8");   // stages tile 14
    TILE(1, NKT - 3, 1, "8");   // stages tile 15
    TILE(0, NKT - 2, 0, "8");
    TILE(1, NKT - 1, 0, "0");

    // epilogue: split q/k/v regions (wn*64 chunks never straddle boundaries)
    const size_t QSZ = (size_t)rows * 1024;
    const size_t KSZ = (size_t)rows * 128;
    const int colg0 = nt * BN + wn * 64;
    float* op;
    int ldc, cb0;
    if (colg0 < 1024)      { op = out;             ldc = 1024; cb0 = colg0; }
    else if (colg0 < 1152) { op = out + QSZ;       ldc = 128;  cb0 = colg0 - 1024; }
    else                   { op = out + QSZ + KSZ; ldc = 128;  cb0 = colg0 - 1152; }

    const size_t r0 = m0 + wm * 64 + ((lane >> 4) * 4);
    const int cc0 = cb0 + (lane & 15);
#pragma unroll
    for (int mi = 0; mi < 4; ++mi)
#pragma unroll
        for (int ni = 0; ni < 4; ++ni)
#pragma unroll
            for (int rr = 0; rr < 4; ++rr)
                op[(r0 + mi * 16 + rr) * (size_t)ldc + cc0 + ni * 16] = acc[mi][ni][rr];
}

// ---------------------------------------------------------------------------
extern "C" void kernel_launch(void* const* d_in, const int* in_sizes, int n_in,
                              void* d_out, int out_size, void* d_ws, size_t ws_size,
                              hipStream_t stream) {
    const float* x   = (const float*)d_in[0];
    const float* lnw = (const float*)d_in[1];
    const float* wq  = (const float*)d_in[2];
    const float* wk  = (const float*)d_in[3];
    const float* wv  = (const float*)d_in[4];
    float* out = (float*)d_out;

    const int rows = in_sizes[0] / H;  // B*S = 32768

    __hip_bfloat16* Bt = (__hip_bfloat16*)d_ws;                               // 2.62 MB
    __hip_bfloat16* h  = (__hip_bfloat16*)((char*)d_ws + (size_t)NTOT * H * 2);

    const int nrms = rows / 4;  // 8192
    k_pre<<<nrms + 320, 256, 0, stream>>>(x, wq, wk, wv, lnw, h, Bt, nrms);
    k_gemm<<<(rows / BM) * NTILES, 256, 0, stream>>>(h, Bt, out, rows);
}